// Round 2
// baseline (297480.176 us; speedup 1.0000x reference)
//
#include <hip/hip_runtime.h>

#define NWG   256
#define TPB   512
#define NSTEP 1000
#define NDATA 2048
#define WIDTH 4096

// ---------- helpers ----------

__device__ __forceinline__ float sp_f(float v) {
  // jax.nn.softplus == max(v,0) + log1p(exp(-|v|))
  return fmaxf(v, 0.0f) + log1pf(expf(-fabsf(v)));
}

__device__ __forceinline__ float dot4(float4 a, float4 b) {
  return a.x * b.x + a.y * b.y + a.z * b.z + a.w * b.w;
}

__device__ __forceinline__ float wred(float v) {
#pragma unroll
  for (int m = 32; m > 0; m >>= 1) v += __shfl_xor(v, m, 64);
  return v;
}

// Decentralized grid barrier — NO atomic RMW contention.
// Arrive: each WG release-stores its own cacheline-padded flag (parallel).
// WG0's threads 1..255 each poll one distinct flag, then WG0 release-stores
// a single `go` flag; all other WGs poll `go` (concurrent reads, pipelined).
// Release fence before arrival publishes data; acquire fence after release
// invalidates stale L1/L2 (per-XCD L2 non-coherence).
__device__ __forceinline__ void gbar(unsigned* arrive, unsigned* go,
                                     unsigned tag, int wg, int tid) {
  __threadfence();          // release this WG's data to the coherence point
  __syncthreads();
  if (wg == 0) {
    if (tid >= 1 && tid < NWG) {
      while (__hip_atomic_load(&arrive[tid * 16], __ATOMIC_RELAXED,
                               __HIP_MEMORY_SCOPE_AGENT) < tag)
        __builtin_amdgcn_s_sleep(1);
    }
    __syncthreads();
    if (tid == 0)
      __hip_atomic_store(go, tag, __ATOMIC_RELEASE, __HIP_MEMORY_SCOPE_AGENT);
  } else {
    if (tid == 0) {
      __hip_atomic_store(&arrive[wg * 16], tag, __ATOMIC_RELEASE,
                         __HIP_MEMORY_SCOPE_AGENT);
      while (__hip_atomic_load(go, __ATOMIC_RELAXED,
                               __HIP_MEMORY_SCOPE_AGENT) < tag)
        __builtin_amdgcn_s_sleep(1);
    }
  }
  __syncthreads();
  __threadfence();          // acquire: invalidate stale cached lines
}

// One wave computes 2 consecutive output rows (64-lane dots, float4 loads).
template<int K, bool SP>
__device__ __forceinline__ void layer2(const float* __restrict__ W,
                                       const float* __restrict__ B,
                                       const float* __restrict__ x,
                                       float* __restrict__ y,
                                       int r0, int lane)
{
  const float4* x4 = (const float4*)x;
  const float4* w0 = (const float4*)(W + (size_t)(r0 + 0) * K);
  const float4* w1 = (const float4*)(W + (size_t)(r0 + 1) * K);
  float a0 = 0.f, a1 = 0.f;
#pragma unroll
  for (int i = 0; i < K / 256; ++i) {
    int o = i * 64 + lane;
    float4 xv = x4[o];
    a0 += dot4(w0[o], xv);
    a1 += dot4(w1[o], xv);
  }
  a0 = wred(a0); a1 = wred(a1);
  if (lane == 0) {
    float v0 = a0 + B[r0 + 0];
    float v1 = a1 + B[r0 + 1];
    if (SP) { v0 = sp_f(v0); v1 = sp_f(v1); }
    y[r0 + 0] = v0; y[r0 + 1] = v1;
  }
}

// Final layer: 1 row per wave; y_new = y_old + dt*(W3 h + b3).
__device__ __forceinline__ void layerF(const float* __restrict__ W,
                                       const float* __restrict__ B,
                                       const float* __restrict__ h,
                                       const float* __restrict__ yold,
                                       float* __restrict__ yout,
                                       float dt, int r, int lane)
{
  const float4* x4 = (const float4*)h;
  const float4* w0 = (const float4*)(W + (size_t)r * WIDTH);
  float a0 = 0.f;
#pragma unroll
  for (int i = 0; i < WIDTH / 256; ++i) {
    int o = i * 64 + lane;
    a0 += dot4(w0[o], x4[o]);
  }
  a0 = wred(a0);
  if (lane == 0) yout[r] = yold[r] + dt * (a0 + B[r]);
}

// ---------- persistent kernel: 1000 steps x 4 layers, flag barriers ----------

__global__ void __launch_bounds__(TPB, 1) ode_persistent(
    const float* __restrict__ ts, const float* __restrict__ y0,
    const float* __restrict__ W0, const float* __restrict__ b0,
    const float* __restrict__ W1, const float* __restrict__ b1,
    const float* __restrict__ W2, const float* __restrict__ b2,
    const float* __restrict__ W3, const float* __restrict__ b3,
    float* __restrict__ out, float* hA, float* hB,
    unsigned* arrive, unsigned* go)
{
  const int wg   = blockIdx.x;
  const int tid  = threadIdx.x;
  const int wave = tid >> 6;
  const int lane = tid & 63;
  const float dt = ts[1] - ts[0];
  const int rw = wg * 16 + wave * 2;  // width layers: 16 rows/WG, 2/wave
  const int rf = wg * 8 + wave;       // final layer: 8 rows/WG, 1/wave
  unsigned tag = 0;
  const float* yin = y0;
  for (int step = 0; step < NSTEP; ++step) {
    layer2<NDATA, true>(W0, b0, yin, hA, rw, lane);
    gbar(arrive, go, ++tag, wg, tid);
    layer2<WIDTH, true>(W1, b1, hA, hB, rw, lane);
    gbar(arrive, go, ++tag, wg, tid);
    layer2<WIDTH, true>(W2, b2, hB, hA, rw, lane);
    gbar(arrive, go, ++tag, wg, tid);
    float* yout = out + (size_t)step * NDATA;
    layerF(W3, b3, hA, yin, yout, dt, rf, lane);
    gbar(arrive, go, ++tag, wg, tid);
    yin = yout;  // y state lives in d_out rows
  }
}

// ---------- launch ----------

extern "C" void kernel_launch(void* const* d_in, const int* in_sizes, int n_in,
                              void* d_out, int out_size, void* d_ws, size_t ws_size,
                              hipStream_t stream) {
  const float* ts = (const float*)d_in[0];
  const float* y0 = (const float*)d_in[1];
  const float* W0 = (const float*)d_in[2];
  const float* b0 = (const float*)d_in[3];
  const float* W1 = (const float*)d_in[4];
  const float* b1 = (const float*)d_in[5];
  const float* W2 = (const float*)d_in[6];
  const float* b2 = (const float*)d_in[7];
  const float* W3 = (const float*)d_in[8];
  const float* b3 = (const float*)d_in[9];
  float* out = (float*)d_out;

  char* ws = (char*)d_ws;
  float*    hA     = (float*)(ws);              // 4096 floats
  float*    hB     = (float*)(ws + 16384);      // 4096 floats
  unsigned* arrive = (unsigned*)(ws + 32768);   // 256 x 16 u32 (1 line/WG)
  unsigned* go     = (unsigned*)(ws + 49152);   // 1 u32 (own line)

  hipMemsetAsync(ws + 32768, 0, 32768, stream); // zero arrive + go each launch
  hipLaunchKernelGGL(ode_persistent, dim3(NWG), dim3(TPB), 0, stream,
                     ts, y0, W0, b0, W1, b1, W2, b2, W3, b3,
                     out, hA, hB, arrive, go);
}

// Round 3
// 60260.022 us; speedup vs baseline: 4.9366x; 4.9366x over previous
//
#include <hip/hip_runtime.h>

#define NWG   256
#define TPB   256
#define NSTEP 1000
#define NDATA 2048
#define WIDTH 4096

typedef __attribute__((ext_vector_type(4))) float f32x4;
typedef __attribute__((ext_vector_type(2))) float f32x2;

// ---------- helpers ----------

__device__ __forceinline__ float sp_f(float v) {
  // jax.nn.softplus == max(v,0) + log1p(exp(-|v|))
  return fmaxf(v, 0.0f) + log1pf(expf(-fabsf(v)));
}

__device__ __forceinline__ float wred(float v) {
#pragma unroll
  for (int m = 32; m > 0; m >>= 1) v += __shfl_xor(v, m, 64);
  return v;
}

// ---- L2-bypass (IC-coherent) activation I/O: sc0 sc1, no cache pollution ----
// Activations are the ONLY cross-XCD data; bypassing L2 for them means NO
// threadfence / buffer_inv is ever needed, so weight lines stay warm in L2.

__device__ __forceinline__ void st_sc_x4(float* p, f32x4 v) {
  asm volatile("global_store_dwordx4 %0, %1, off sc0 sc1" :: "v"(p), "v"(v) : "memory");
}
__device__ __forceinline__ void st_sc_x2(float* p, f32x2 v) {
  asm volatile("global_store_dwordx2 %0, %1, off sc0 sc1" :: "v"(p), "v"(v) : "memory");
}
__device__ __forceinline__ f32x2 ld_sc_x2(const float* p) {
  f32x2 v;
  asm volatile("global_load_dwordx2 %0, %1, off sc0 sc1\n\t"
               "s_waitcnt vmcnt(0)" : "=v"(v) : "v"(p) : "memory");
  return v;
}

// Stage a 4096-float activation vector into LDS via bypass loads (4/thread).
__device__ __forceinline__ void stage_x4096(const float* src, float* xs, int tid) {
  const f32x4* s = (const f32x4*)src;
  const f32x4 *p0 = s + tid, *p1 = s + tid + 256, *p2 = s + tid + 512, *p3 = s + tid + 768;
  f32x4 a, b, c, d;
  asm volatile(
      "global_load_dwordx4 %0, %4, off sc0 sc1\n\t"
      "global_load_dwordx4 %1, %5, off sc0 sc1\n\t"
      "global_load_dwordx4 %2, %6, off sc0 sc1\n\t"
      "global_load_dwordx4 %3, %7, off sc0 sc1\n\t"
      "s_waitcnt vmcnt(0)"
      : "=v"(a), "=v"(b), "=v"(c), "=v"(d)
      : "v"(p0), "v"(p1), "v"(p2), "v"(p3) : "memory");
  f32x4* l = (f32x4*)xs;
  l[tid] = a; l[tid + 256] = b; l[tid + 512] = c; l[tid + 768] = d;
  __syncthreads();
}

// Stage a 2048-float activation vector into LDS (2/thread).
__device__ __forceinline__ void stage_x2048(const float* src, float* xs, int tid) {
  const f32x4* s = (const f32x4*)src;
  const f32x4 *p0 = s + tid, *p1 = s + tid + 256;
  f32x4 a, b;
  asm volatile(
      "global_load_dwordx4 %0, %2, off sc0 sc1\n\t"
      "global_load_dwordx4 %1, %3, off sc0 sc1\n\t"
      "s_waitcnt vmcnt(0)"
      : "=v"(a), "=v"(b) : "v"(p0), "v"(p1) : "memory");
  f32x4* l = (f32x4*)xs;
  l[tid] = a; l[tid + 256] = b;
  __syncthreads();
}

// Fence-free grid barrier: monotonic two-level counter tree, relaxed
// agent-scope atomics (execute at the IC = coherence point; per-line RMW
// serialization capped at 16). NO buffer_wbl2 / buffer_inv anywhere.
// Ordering: every thread drains its bypass stores (vmcnt(0)) before
// __syncthreads; tid0 then arrives. Data is IC-resident when root advances.
__device__ __forceinline__ void gbar(unsigned* gcnt, unsigned* root,
                                     unsigned b, int wg, int tid) {
  asm volatile("s_waitcnt vmcnt(0)" ::: "memory");
  __syncthreads();
  if (tid == 0) {
    unsigned old = __hip_atomic_fetch_add(&gcnt[(wg >> 4) * 16], 1u,
                                          __ATOMIC_RELAXED, __HIP_MEMORY_SCOPE_AGENT);
    if ((old & 15u) == 15u)
      __hip_atomic_fetch_add(root, 1u, __ATOMIC_RELAXED, __HIP_MEMORY_SCOPE_AGENT);
    const unsigned target = 16u * (b + 1u);
    while (__hip_atomic_load(root, __ATOMIC_RELAXED, __HIP_MEMORY_SCOPE_AGENT) < target)
      __builtin_amdgcn_s_sleep(2);
  }
  __syncthreads();
}

// One wave computes 4 consecutive rows; weights plain cached loads, x from LDS.
template<int K, bool SP>
__device__ __forceinline__ void layer4(const float* __restrict__ W,
                                       const float* __restrict__ B,
                                       const float* __restrict__ xs,
                                       float* __restrict__ y,
                                       int r0, int lane)
{
  const f32x4* x4 = (const f32x4*)xs;
  const f32x4* w0 = (const f32x4*)(W + (size_t)(r0 + 0) * K);
  const f32x4* w1 = (const f32x4*)(W + (size_t)(r0 + 1) * K);
  const f32x4* w2 = (const f32x4*)(W + (size_t)(r0 + 2) * K);
  const f32x4* w3 = (const f32x4*)(W + (size_t)(r0 + 3) * K);
  float a0 = 0.f, a1 = 0.f, a2 = 0.f, a3 = 0.f;
#pragma unroll
  for (int i = 0; i < K / 256; ++i) {
    int o = i * 64 + lane;
    f32x4 xv = x4[o];
    f32x4 v0 = w0[o], v1 = w1[o], v2 = w2[o], v3 = w3[o];
    a0 += v0.x*xv.x + v0.y*xv.y + v0.z*xv.z + v0.w*xv.w;
    a1 += v1.x*xv.x + v1.y*xv.y + v1.z*xv.z + v1.w*xv.w;
    a2 += v2.x*xv.x + v2.y*xv.y + v2.z*xv.z + v2.w*xv.w;
    a3 += v3.x*xv.x + v3.y*xv.y + v3.z*xv.z + v3.w*xv.w;
  }
  a0 = wred(a0); a1 = wred(a1); a2 = wred(a2); a3 = wred(a3);
  if (lane == 0) {
    f32x4 v;
    v.x = a0 + B[r0 + 0]; v.y = a1 + B[r0 + 1];
    v.z = a2 + B[r0 + 2]; v.w = a3 + B[r0 + 3];
    if (SP) { v.x = sp_f(v.x); v.y = sp_f(v.y); v.z = sp_f(v.z); v.w = sp_f(v.w); }
    st_sc_x4(y + r0, v);
  }
}

// Final layer: 2 rows/wave; y_new = y_old + dt*(W3 h + b3); bypass I/O on y.
__device__ __forceinline__ void layerF(const float* __restrict__ W,
                                       const float* __restrict__ B,
                                       const float* __restrict__ xs,
                                       const float* __restrict__ yold,
                                       float* __restrict__ yout,
                                       float dt, int r0, int lane)
{
  const f32x4* x4 = (const f32x4*)xs;
  const f32x4* w0 = (const f32x4*)(W + (size_t)(r0 + 0) * WIDTH);
  const f32x4* w1 = (const f32x4*)(W + (size_t)(r0 + 1) * WIDTH);
  float a0 = 0.f, a1 = 0.f;
#pragma unroll
  for (int i = 0; i < WIDTH / 256; ++i) {
    int o = i * 64 + lane;
    f32x4 xv = x4[o];
    f32x4 v0 = w0[o], v1 = w1[o];
    a0 += v0.x*xv.x + v0.y*xv.y + v0.z*xv.z + v0.w*xv.w;
    a1 += v1.x*xv.x + v1.y*xv.y + v1.z*xv.z + v1.w*xv.w;
  }
  a0 = wred(a0); a1 = wred(a1);
  if (lane == 0) {
    f32x2 yo = ld_sc_x2(yold + r0);
    f32x2 v;
    v.x = yo.x + dt * (a0 + B[r0 + 0]);
    v.y = yo.y + dt * (a1 + B[r0 + 1]);
    st_sc_x2(yout + r0, v);
  }
}

// ---------- persistent kernel ----------

__global__ void __launch_bounds__(TPB, 1) ode_persistent(
    const float* __restrict__ ts, const float* __restrict__ y0,
    const float* __restrict__ W0, const float* __restrict__ b0,
    const float* __restrict__ W1, const float* __restrict__ b1,
    const float* __restrict__ W2, const float* __restrict__ b2,
    const float* __restrict__ W3, const float* __restrict__ b3,
    float* __restrict__ out, float* hA, float* hB,
    unsigned* gcnt, unsigned* root)
{
  __shared__ float xs[WIDTH];
  const int wg   = blockIdx.x;
  const int tid  = threadIdx.x;
  const int wave = tid >> 6;
  const int lane = tid & 63;
  const float dt = ts[1] - ts[0];
  const int rw = wg * 16 + wave * 4;  // width layers: 16 rows/WG, 4/wave
  const int rf = wg * 8 + wave * 2;   // final layer: 8 rows/WG, 2/wave
  unsigned b = 0;
  const float* yin = y0;
  for (int step = 0; step < NSTEP; ++step) {
    stage_x2048(yin, xs, tid);
    layer4<NDATA, true>(W0, b0, xs, hA, rw, lane);
    gbar(gcnt, root, b++, wg, tid);
    stage_x4096(hA, xs, tid);
    layer4<WIDTH, true>(W1, b1, xs, hB, rw, lane);
    gbar(gcnt, root, b++, wg, tid);
    stage_x4096(hB, xs, tid);
    layer4<WIDTH, true>(W2, b2, xs, hA, rw, lane);
    gbar(gcnt, root, b++, wg, tid);
    stage_x4096(hA, xs, tid);
    float* yout = out + (size_t)step * NDATA;
    layerF(W3, b3, xs, yin, yout, dt, rf, lane);
    gbar(gcnt, root, b++, wg, tid);
    yin = yout;  // y state lives in d_out rows
  }
}

// ---------- launch ----------

extern "C" void kernel_launch(void* const* d_in, const int* in_sizes, int n_in,
                              void* d_out, int out_size, void* d_ws, size_t ws_size,
                              hipStream_t stream) {
  const float* ts = (const float*)d_in[0];
  const float* y0 = (const float*)d_in[1];
  const float* W0 = (const float*)d_in[2];
  const float* b0 = (const float*)d_in[3];
  const float* W1 = (const float*)d_in[4];
  const float* b1 = (const float*)d_in[5];
  const float* W2 = (const float*)d_in[6];
  const float* b2 = (const float*)d_in[7];
  const float* W3 = (const float*)d_in[8];
  const float* b3 = (const float*)d_in[9];
  float* out = (float*)d_out;

  char* ws = (char*)d_ws;
  float*    hA   = (float*)(ws);                // 4096 floats
  float*    hB   = (float*)(ws + 16384);        // 4096 floats
  unsigned* gcnt = (unsigned*)(ws + 32768);     // 16 groups x 16 u32 (64B apart)
  unsigned* root = (unsigned*)(ws + 32768 + 1024);

  hipMemsetAsync(ws + 32768, 0, 4096, stream);  // zero counters each launch
  hipLaunchKernelGGL(ode_persistent, dim3(NWG), dim3(TPB), 0, stream,
                     ts, y0, W0, b0, W1, b1, W2, b2, W3, b3,
                     out, hA, hB, gcnt, root);
}

// Round 4
// 57944.574 us; speedup vs baseline: 5.1339x; 1.0400x over previous
//
#include <hip/hip_runtime.h>

#define NWG   256
#define TPB   1024
#define NSTEP 1000
#define NDATA 2048
#define WIDTH 4096

typedef __attribute__((ext_vector_type(4))) float f32x4;

// ---------- helpers ----------

__device__ __forceinline__ float sp_f(float v) {
  // jax.nn.softplus == max(v,0) + log1p(exp(-|v|))
  return fmaxf(v, 0.0f) + log1pf(expf(-fabsf(v)));
}

__device__ __forceinline__ float wred(float v) {
#pragma unroll
  for (int m = 32; m > 0; m >>= 1) v += __shfl_xor(v, m, 64);
  return v;
}

// ---- L2-bypass (IC-coherent) activation I/O: sc0 sc1, no cache pollution ----
// Activations are the ONLY cross-XCD data; bypassing L2 for them means NO
// threadfence / buffer_inv is ever needed, so weight lines stay warm in L2/IC.

__device__ __forceinline__ void st_sc_x1(float* p, float v) {
  asm volatile("global_store_dword %0, %1, off sc0 sc1" :: "v"(p), "v"(v) : "memory");
}
__device__ __forceinline__ float ld_sc_x1(const float* p) {
  float v;
  asm volatile("global_load_dword %0, %1, off sc0 sc1\n\t"
               "s_waitcnt vmcnt(0)" : "=v"(v) : "v"(p) : "memory");
  return v;
}

// Stage a 4096-float activation vector into LDS via bypass loads (x4/thread).
__device__ __forceinline__ void stage_x4096(const float* src, float* xs, int tid) {
  const f32x4* s = (const f32x4*)src + tid;
  f32x4 a;
  asm volatile("global_load_dwordx4 %0, %1, off sc0 sc1\n\t"
               "s_waitcnt vmcnt(0)" : "=v"(a) : "v"(s) : "memory");
  ((f32x4*)xs)[tid] = a;
  __syncthreads();
}

// Stage a 2048-float activation vector into LDS (threads 0..511).
__device__ __forceinline__ void stage_x2048(const float* src, float* xs, int tid) {
  if (tid < 512) {
    const f32x4* s = (const f32x4*)src + tid;
    f32x4 a;
    asm volatile("global_load_dwordx4 %0, %1, off sc0 sc1\n\t"
                 "s_waitcnt vmcnt(0)" : "=v"(a) : "v"(s) : "memory");
    ((f32x4*)xs)[tid] = a;
  }
  __syncthreads();
}

// Fence-free grid barrier: monotonic two-level counter tree, relaxed
// agent-scope atomics (execute at the coherence point; per-line RMW
// serialization capped at 16). NO buffer_wbl2 / buffer_inv anywhere.
// Ordering: every thread drains its bypass stores (vmcnt(0)) before
// __syncthreads; tid0 then arrives. Data is IC-resident when root advances.
__device__ __forceinline__ void gbar(unsigned* gcnt, unsigned* root,
                                     unsigned b, int wg, int tid) {
  asm volatile("s_waitcnt vmcnt(0)" ::: "memory");
  __syncthreads();
  if (tid == 0) {
    unsigned old = __hip_atomic_fetch_add(&gcnt[(wg >> 4) * 16], 1u,
                                          __ATOMIC_RELAXED, __HIP_MEMORY_SCOPE_AGENT);
    if ((old & 15u) == 15u)
      __hip_atomic_fetch_add(root, 1u, __ATOMIC_RELAXED, __HIP_MEMORY_SCOPE_AGENT);
    const unsigned target = 16u * (b + 1u);
    while (__hip_atomic_load(root, __ATOMIC_RELAXED, __HIP_MEMORY_SCOPE_AGENT) < target)
      __builtin_amdgcn_s_sleep(2);
  }
  __syncthreads();
}

// One wave computes ONE output row: issue the whole row's weight loads
// back-to-back (max loads in flight), then accumulate against LDS x.
template<int K, bool SP>
__device__ __forceinline__ void layer1(const float* __restrict__ W,
                                       const float* __restrict__ B,
                                       const float* __restrict__ xs,
                                       float* __restrict__ y,
                                       int r, int lane)
{
  constexpr int NI = K / 256;              // 8 (K=2048) or 16 (K=4096)
  const f32x4* w = (const f32x4*)(W + (size_t)r * K);
  const f32x4* x4 = (const f32x4*)xs;
  f32x4 wr[NI];
#pragma unroll
  for (int i = 0; i < NI; ++i) wr[i] = w[i * 64 + lane];
  float a = 0.f;
#pragma unroll
  for (int i = 0; i < NI; ++i) {
    f32x4 xv = x4[i * 64 + lane];
    a += wr[i].x * xv.x + wr[i].y * xv.y + wr[i].z * xv.z + wr[i].w * xv.w;
  }
  a = wred(a);
  if (lane == 0) {
    float v = a + B[r];
    if (SP) v = sp_f(v);
    st_sc_x1(y + r, v);
  }
}

// Final layer: 8 rows/WG, 2 waves per row (each does half of K=4096),
// partials combined through LDS. y_new = y_old + dt*(W3 h + b3).
__device__ __forceinline__ void layerF(const float* __restrict__ W,
                                       const float* __restrict__ B,
                                       const float* __restrict__ xs,
                                       const float* __restrict__ yin,
                                       float* __restrict__ yout,
                                       float* __restrict__ ps,
                                       float dt, int wg, int wave, int lane)
{
  const int r    = wg * 8 + (wave >> 1);
  const int half = wave & 1;
  constexpr int NI = 8;                    // 2048 elements per half-row
  const f32x4* w = (const f32x4*)(W + (size_t)r * WIDTH) + half * 512;
  const f32x4* x4 = (const f32x4*)xs + half * 512;
  f32x4 wr[NI];
#pragma unroll
  for (int i = 0; i < NI; ++i) wr[i] = w[i * 64 + lane];
  float a = 0.f;
#pragma unroll
  for (int i = 0; i < NI; ++i) {
    f32x4 xv = x4[i * 64 + lane];
    a += wr[i].x * xv.x + wr[i].y * xv.y + wr[i].z * xv.z + wr[i].w * xv.w;
  }
  a = wred(a);
  if (lane == 0) ps[wave] = a;
  __syncthreads();
  if (half == 0 && lane == 0) {
    float tot = ps[wave] + ps[wave + 1];
    float yo  = ld_sc_x1(yin + r);
    st_sc_x1(yout + r, yo + dt * (tot + B[r]));
  }
}

// ---------- persistent kernel: 1000 steps x 4 layers, flag barriers ----------

__global__ void __launch_bounds__(TPB, 1) ode_persistent(
    const float* __restrict__ ts, const float* __restrict__ y0,
    const float* __restrict__ W0, const float* __restrict__ b0,
    const float* __restrict__ W1, const float* __restrict__ b1,
    const float* __restrict__ W2, const float* __restrict__ b2,
    const float* __restrict__ W3, const float* __restrict__ b3,
    float* __restrict__ out, float* hA, float* hB,
    unsigned* gcnt, unsigned* root)
{
  __shared__ float xs[WIDTH];
  __shared__ float ps[16];
  const int wg   = blockIdx.x;
  const int tid  = threadIdx.x;
  const int wave = tid >> 6;
  const int lane = tid & 63;
  const float dt = ts[1] - ts[0];
  const int rw = wg * 16 + wave;      // width layers: 16 rows/WG, 1/wave
  unsigned b = 0;
  const float* yin = y0;
  for (int step = 0; step < NSTEP; ++step) {
    stage_x2048(yin, xs, tid);
    layer1<NDATA, true>(W0, b0, xs, hA, rw, lane);
    gbar(gcnt, root, b++, wg, tid);
    stage_x4096(hA, xs, tid);
    layer1<WIDTH, true>(W1, b1, xs, hB, rw, lane);
    gbar(gcnt, root, b++, wg, tid);
    stage_x4096(hB, xs, tid);
    layer1<WIDTH, true>(W2, b2, xs, hA, rw, lane);
    gbar(gcnt, root, b++, wg, tid);
    stage_x4096(hA, xs, tid);
    float* yout = out + (size_t)step * NDATA;
    layerF(W3, b3, xs, yin, yout, ps, dt, wg, wave, lane);
    gbar(gcnt, root, b++, wg, tid);
    yin = yout;  // y state lives in d_out rows
  }
}

// ---------- launch ----------

extern "C" void kernel_launch(void* const* d_in, const int* in_sizes, int n_in,
                              void* d_out, int out_size, void* d_ws, size_t ws_size,
                              hipStream_t stream) {
  const float* ts = (const float*)d_in[0];
  const float* y0 = (const float*)d_in[1];
  const float* W0 = (const float*)d_in[2];
  const float* b0 = (const float*)d_in[3];
  const float* W1 = (const float*)d_in[4];
  const float* b1 = (const float*)d_in[5];
  const float* W2 = (const float*)d_in[6];
  const float* b2 = (const float*)d_in[7];
  const float* W3 = (const float*)d_in[8];
  const float* b3 = (const float*)d_in[9];
  float* out = (float*)d_out;

  char* ws = (char*)d_ws;
  float*    hA   = (float*)(ws);                // 4096 floats
  float*    hB   = (float*)(ws + 16384);        // 4096 floats
  unsigned* gcnt = (unsigned*)(ws + 32768);     // 16 groups x 16 u32 (64B apart)
  unsigned* root = (unsigned*)(ws + 32768 + 1024);

  hipMemsetAsync(ws + 32768, 0, 4096, stream);  // zero counters each launch
  hipLaunchKernelGGL(ode_persistent, dim3(NWG), dim3(TPB), 0, stream,
                     ts, y0, W0, b0, W1, b1, W2, b2, W3, b3,
                     out, hA, hB, gcnt, root);
}

// Round 5
// 37900.967 us; speedup vs baseline: 7.8489x; 1.5288x over previous
//
#include <hip/hip_runtime.h>
#include <type_traits>

#define NWG   256
#define TPB   1024
#define NSTEP 1000
#define NDATA 2048
#define WIDTH 4096

typedef __attribute__((ext_vector_type(4))) float f32x4;
typedef __attribute__((ext_vector_type(2))) unsigned int u32x2;
typedef unsigned int uint;

#define SCHED_FENCE() __builtin_amdgcn_sched_barrier(0)

// ---------- scalar helpers ----------

__device__ __forceinline__ float sp_f(float v) {
  // jax.nn.softplus == max(v,0) + log1p(exp(-|v|))
  return fmaxf(v, 0.0f) + log1pf(expf(-fabsf(v)));
}

__device__ __forceinline__ float wred(float v) {
#pragma unroll
  for (int m = 32; m > 0; m >>= 1) v += __shfl_xor(v, m, 64);
  return v;
}

// ---------- waits / barriers (raw: compiler adds NO implicit drains) ----------

__device__ __forceinline__ void wait_vm0()   { asm volatile("s_waitcnt vmcnt(0)" ::: "memory"); SCHED_FENCE(); }
template<int N>
__device__ __forceinline__ void wait_vmN()   { asm volatile("s_waitcnt vmcnt(%0)" :: "n"(N) : "memory"); SCHED_FENCE(); }
__device__ __forceinline__ void wait_lgkm0() { asm volatile("s_waitcnt lgkmcnt(0)" ::: "memory"); SCHED_FENCE(); }
__device__ __forceinline__ void wgbar()      { __builtin_amdgcn_s_barrier(); SCHED_FENCE(); }

// ---------- L2-bypass (coherent) activation I/O ----------

__device__ __forceinline__ void st_sc_x1(float* p, float v) {
  asm volatile("global_store_dword %0, %1, off sc0 sc1" :: "v"(p), "v"(v) : "memory");
}
__device__ __forceinline__ void ld_sc_x1_issue(const float* p, float& v) {
  asm volatile("global_load_dword %0, %1, off sc0 sc1" : "=v"(v) : "v"(p) : "memory");
}
__device__ __forceinline__ void ld_sc_x4_issue(const f32x4* p, f32x4& v) {
  asm volatile("global_load_dwordx4 %0, %1, off sc0 sc1" : "=v"(v) : "v"(p) : "memory");
}

// ---------- weight prefetch: cached loads, issue-only, stay in flight ----------

template<bool BF16, int NI, typename WB>
__device__ __forceinline__ void issue_row(const void* W, size_t elemidx, int lane, WB* wr) {
  if constexpr (BF16) {
    const u32x2* p = (const u32x2*)((const uint*)W + (elemidx >> 1)) + lane;
#pragma unroll
    for (int i = 0; i < NI; ++i)
      asm volatile("global_load_dwordx2 %0, %1, off" : "=v"(wr[i]) : "v"(p + i * 64) : "memory");
  } else {
    const f32x4* p = (const f32x4*)((const float*)W + elemidx) + lane;
#pragma unroll
    for (int i = 0; i < NI; ++i)
      asm volatile("global_load_dwordx4 %0, %1, off" : "=v"(wr[i]) : "v"(p + i * 64) : "memory");
  }
}

// ---------- dot of one row-chunk set against LDS x ----------

template<int NI>
__device__ __forceinline__ float dot_row(const u32x2* wr, const float* xs, int xoff, int lane) {
  const f32x4* x4 = (const f32x4*)xs + xoff;
  float a = 0.f;
#pragma unroll
  for (int i = 0; i < NI; ++i) {
    f32x4 xv = x4[i * 64 + lane];
    uint w01 = wr[i].x, w23 = wr[i].y;
    a = fmaf(__uint_as_float(w01 << 16),          xv.x, a);
    a = fmaf(__uint_as_float(w01 & 0xffff0000u),  xv.y, a);
    a = fmaf(__uint_as_float(w23 << 16),          xv.z, a);
    a = fmaf(__uint_as_float(w23 & 0xffff0000u),  xv.w, a);
  }
  return a;
}

template<int NI>
__device__ __forceinline__ float dot_row(const f32x4* wr, const float* xs, int xoff, int lane) {
  const f32x4* x4 = (const f32x4*)xs + xoff;
  float a = 0.f;
#pragma unroll
  for (int i = 0; i < NI; ++i) {
    f32x4 xv = x4[i * 64 + lane];
    a = fmaf(wr[i].x, xv.x, a); a = fmaf(wr[i].y, xv.y, a);
    a = fmaf(wr[i].z, xv.z, a); a = fmaf(wr[i].w, xv.w, a);
  }
  return a;
}

// ---------- activation staging into LDS (bypass loads) ----------

__device__ __forceinline__ void stage4096(const float* src, float* xs, int tid) {
  f32x4 a;
  ld_sc_x4_issue((const f32x4*)src + tid, a);
  wait_vm0();                       // also drains this layer's weight prefetch (needed next)
  ((f32x4*)xs)[tid] = a;
  wait_lgkm0();
  wgbar();
}

__device__ __forceinline__ void stage2048(const float* src, float* xs, int tid) {
  f32x4 a;
  bool act = tid < 512;
  if (act) ld_sc_x4_issue((const f32x4*)src + tid, a);
  wait_vm0();
  if (act) ((f32x4*)xs)[tid] = a;
  wait_lgkm0();
  wgbar();
}

// ---------- fence-free grid barrier (monotonic 2-level counter tree) ----------
// Caller guarantees: every wave drained its activation store (counted vmcnt)
// BEFORE calling. Weight prefetch loads stay in flight across this barrier.

__device__ __forceinline__ void gbar(unsigned* gcnt, unsigned* root,
                                     unsigned b, int wg, int tid) {
  wgbar();
  if (tid == 0) {
    unsigned old = __hip_atomic_fetch_add(&gcnt[(wg >> 4) * 16], 1u,
                                          __ATOMIC_RELAXED, __HIP_MEMORY_SCOPE_AGENT);
    if ((old & 15u) == 15u)
      __hip_atomic_fetch_add(root, 1u, __ATOMIC_RELAXED, __HIP_MEMORY_SCOPE_AGENT);
    const unsigned target = 16u * (b + 1u);
    while (__hip_atomic_load(root, __ATOMIC_RELAXED, __HIP_MEMORY_SCOPE_AGENT) < target)
      __builtin_amdgcn_s_sleep(1);
  }
  wgbar();
}

// ---------- fp32 -> bf16 (RNE) weight conversion ----------

__device__ __forceinline__ uint bfr(float f) {
  uint u = __float_as_uint(f);
  return (u + 0x7fffu + ((u >> 16) & 1u)) >> 16;
}

__global__ void cvt_bf16(const float* __restrict__ in, uint* __restrict__ out, int n4) {
  int i = blockIdx.x * 256 + threadIdx.x;
  if (i >= n4) return;
  f32x4 v = ((const f32x4*)in)[i];
  u32x2 o;
  o.x = bfr(v.x) | (bfr(v.y) << 16);
  o.y = bfr(v.z) | (bfr(v.w) << 16);
  ((u32x2*)out)[i] = o;
}

// ---------- persistent kernel ----------
// Structure per layer: [weights already in flight] -> gbar passed -> stage x
// (vmcnt(0): x + weights land) -> FMA dot -> store act (bypass) -> issue NEXT
// layer's weight loads -> vmcnt(N) (drains store, loads stay in flight) ->
// gbar (loads stream during arrival+poll).

template<bool BF16>
__global__ void __launch_bounds__(TPB, 1) ode_persistent(
    const float* __restrict__ ts, const float* __restrict__ y0,
    const void* __restrict__ W0, const float* __restrict__ b0,
    const void* __restrict__ W1, const float* __restrict__ b1,
    const void* __restrict__ W2, const float* __restrict__ b2,
    const void* __restrict__ W3, const float* __restrict__ b3,
    float* __restrict__ out, float* hA, float* hB,
    unsigned* gcnt, unsigned* root)
{
  using WB = typename std::conditional<BF16, u32x2, f32x4>::type;
  __shared__ float xs[WIDTH];
  __shared__ float ps[16];
  const int wg = blockIdx.x, tid = threadIdx.x;
  const int wave = tid >> 6, lane = tid & 63;
  const float dt = ts[1] - ts[0];
  const int rw = wg * 16 + wave;          // width layers: 1 row/wave
  const int rF = wg * 8 + (wave >> 1);    // final layer: 2 waves/row
  const int hf = wave & 1;

  WB w0r[8], w1r[16], w2r[16], w3r[8];
  issue_row<BF16, 8>(W0, (size_t)rw * NDATA, lane, w0r);   // prologue prefetch

  unsigned b = 0;
  const float* yin = y0;
  for (int step = 0; step < NSTEP; ++step) {
    // ---- L0: 2048 -> 4096, softplus ----
    stage2048(yin, xs, tid);
    float a = wred(dot_row<8>(w0r, xs, 0, lane));
    if (lane == 0) st_sc_x1(hA + rw, sp_f(a + b0[rw]));
    issue_row<BF16, 16>(W1, (size_t)rw * WIDTH, lane, w1r);
    wait_vmN<16>();                       // store drained; 16 loads in flight
    gbar(gcnt, root, b++, wg, tid);

    // ---- L1: 4096 -> 4096, softplus ----
    stage4096(hA, xs, tid);
    a = wred(dot_row<16>(w1r, xs, 0, lane));
    if (lane == 0) st_sc_x1(hB + rw, sp_f(a + b1[rw]));
    issue_row<BF16, 16>(W2, (size_t)rw * WIDTH, lane, w2r);
    wait_vmN<16>();
    gbar(gcnt, root, b++, wg, tid);

    // ---- L2: 4096 -> 4096, softplus ----
    stage4096(hB, xs, tid);
    a = wred(dot_row<16>(w2r, xs, 0, lane));
    if (lane == 0) st_sc_x1(hA + rw, sp_f(a + b2[rw]));
    issue_row<BF16, 8>(W3, (size_t)rF * WIDTH + (size_t)hf * 2048, lane, w3r);
    wait_vmN<8>();
    gbar(gcnt, root, b++, wg, tid);

    // ---- LF: 4096 -> 2048, y += dt*(W3 h + b3); 2 waves/row split-K ----
    stage4096(hA, xs, tid);
    float yo;
    ld_sc_x1_issue(yin + rF, yo);         // in flight during dot
    a = wred(dot_row<8>(w3r, xs, hf * 512, lane));
    if (lane == 0) ps[wave] = a;
    wait_lgkm0();
    wgbar();                              // ps visible
    wait_vm0();                           // yo ready
    float* yout = out + (size_t)step * NDATA;
    if (hf == 0 && lane == 0) {
      float tot = ps[wave] + ps[wave + 1];
      st_sc_x1(yout + rF, yo + dt * (tot + b3[rF]));
    }
    issue_row<BF16, 8>(W0, (size_t)rw * NDATA, lane, w0r);  // next step's L0
    wait_vmN<8>();                        // drains y store (hf==0 waves)
    gbar(gcnt, root, b++, wg, tid);
    yin = yout;                           // y state lives in d_out rows
  }
}

// ---------- launch ----------

#define WS_HA   0
#define WS_HB   16384
#define WS_CNT  32768
#define WS_WB   65536
static const size_t N_W0 = (size_t)WIDTH * NDATA;   // 8.39M
static const size_t N_W1 = (size_t)WIDTH * WIDTH;   // 16.78M
static const size_t N_W3 = (size_t)NDATA * WIDTH;   // 8.39M

extern "C" void kernel_launch(void* const* d_in, const int* in_sizes, int n_in,
                              void* d_out, int out_size, void* d_ws, size_t ws_size,
                              hipStream_t stream) {
  const float* ts = (const float*)d_in[0];
  const float* y0 = (const float*)d_in[1];
  const float* W0 = (const float*)d_in[2];
  const float* b0 = (const float*)d_in[3];
  const float* W1 = (const float*)d_in[4];
  const float* b1 = (const float*)d_in[5];
  const float* W2 = (const float*)d_in[6];
  const float* b2 = (const float*)d_in[7];
  const float* W3 = (const float*)d_in[8];
  const float* b3 = (const float*)d_in[9];
  float* out = (float*)d_out;

  char* ws = (char*)d_ws;
  float*    hA   = (float*)(ws + WS_HA);
  float*    hB   = (float*)(ws + WS_HB);
  unsigned* gcnt = (unsigned*)(ws + WS_CNT);
  unsigned* root = (unsigned*)(ws + WS_CNT + 1024);

  hipMemsetAsync(ws + WS_CNT, 0, 4096, stream);

  const size_t need = WS_WB + (N_W0 + 2 * N_W1 + N_W3) * 2;  // ~100.7 MB
  if (ws_size >= need) {
    uint* W0b = (uint*)(ws + WS_WB);
    uint* W1b = W0b + N_W0 / 2;
    uint* W2b = W1b + N_W1 / 2;
    uint* W3b = W2b + N_W1 / 2;
    hipLaunchKernelGGL(cvt_bf16, dim3((unsigned)(N_W0 / 4 / 256)), dim3(256), 0, stream, W0, W0b, (int)(N_W0 / 4));
    hipLaunchKernelGGL(cvt_bf16, dim3((unsigned)(N_W1 / 4 / 256)), dim3(256), 0, stream, W1, W1b, (int)(N_W1 / 4));
    hipLaunchKernelGGL(cvt_bf16, dim3((unsigned)(N_W1 / 4 / 256)), dim3(256), 0, stream, W2, W2b, (int)(N_W1 / 4));
    hipLaunchKernelGGL(cvt_bf16, dim3((unsigned)(N_W3 / 4 / 256)), dim3(256), 0, stream, W3, W3b, (int)(N_W3 / 4));
    hipLaunchKernelGGL(ode_persistent<true>, dim3(NWG), dim3(TPB), 0, stream,
                       ts, y0, W0b, b0, W1b, b1, W2b, b2, W3b, b3,
                       out, hA, hB, gcnt, root);
  } else {
    hipLaunchKernelGGL(ode_persistent<false>, dim3(NWG), dim3(TPB), 0, stream,
                       ts, y0, W0, b0, W1, b1, W2, b2, W3, b3,
                       out, hA, hB, gcnt, root);
  }
}